// Round 1
// baseline (369.473 us; speedup 1.0000x reference)
//
#include <hip/hip_runtime.h>
#include <math.h>

#define BB 128
#define TT 1024
#define NN 64

__device__ __forceinline__ float wave_sum64(float v) {
#pragma unroll
  for (int o = 32; o > 0; o >>= 1) v += __shfl_xor(v, o, 64);
  return v;
}

// Grid: 256 blocks x 64 threads.
//  blocks [0,128)   : forward-algorithm scan (log-normalizer) for batch b = blockIdx
//  blocks [128,256) : unary+binary sequence score for batch b = blockIdx-128
// Results: ws[b] = log_norm[b], ws[128+b] = seq_score[b]
__global__ __launch_bounds__(64) void crf_main(
    const float* __restrict__ pot,    // [B,T,N]
    const int*   __restrict__ tags,   // [B,T]
    const int*   __restrict__ seqlen, // [B]
    const float* __restrict__ K,      // [N,N]
    float* __restrict__ ws) {
  __shared__ float sh[4096];  // score path: staged K; scan path: a double-buffer (first 128 floats)
  const int lane = threadIdx.x;
  const int blk  = blockIdx.x;

  if (blk < BB) {
    // ---------------- scan: linear-space forward algorithm ----------------
    const int b = blk;
    const int L = seqlen[b];

    // E column for this lane: Ec[i] = exp(K[i][lane])
    float Ec[64];
#pragma unroll
    for (int i = 0; i < 64; i++) Ec[i] = __expf(K[i * 64 + lane]);

    const float* pb = pot + (size_t)b * TT * NN + lane;  // element (b, t, lane) at pb[t*64]

    float av = __expf(pb[0]);  // a_0 = exp(alpha_0) = exp(pot[b,0,:])
    int etot = 0;              // accumulated power-of-2 rescale exponent
    sh[lane] = av;             // buffer 0 holds a_{0}

    // software prefetch ring, depth 8 (t = 1..8)
    float pf[8];
#pragma unroll
    for (int k = 0; k < 8; k++) pf[k] = pb[(size_t)(1 + k) * 64];

    for (int t0 = 1; t0 < L; t0 += 8) {  // t0 is always == 1 (mod 8)
#pragma unroll
      for (int k = 0; k < 8; k++) {
        const int t = t0 + k;
        const float pe = __expf(pf[k]);          // exp(pot[b,t,lane]) (off critical path)
        int tn = t + 8; tn = tn > (TT - 1) ? (TT - 1) : tn;
        pf[k] = pb[(size_t)tn * 64];             // refill prefetch slot (t+8)

        // dot: S = sum_i a_prev[i] * E[i][lane], a_prev broadcast from LDS
        const float4* arow = (const float4*)(sh + ((t - 1) & 1) * 64);
        float s[8];
#pragma unroll
        for (int q = 0; q < 8; q++) s[q] = 0.0f;
#pragma unroll
        for (int q = 0; q < 16; q++) {
          float4 a4 = arow[q];
          float pr = fmaf(a4.x, Ec[4 * q + 0],
                     fmaf(a4.y, Ec[4 * q + 1],
                     fmaf(a4.z, Ec[4 * q + 2], a4.w * Ec[4 * q + 3])));
          s[q & 7] += pr;
        }
        float S = ((s[0] + s[1]) + (s[2] + s[3])) + ((s[4] + s[5]) + (s[6] + s[7]));

        if (t < L) {  // wave-uniform predicate (frozen past sequence end)
          av = S * pe;
          if ((t & 3) == 0) {
            // exact power-of-2 renorm; lane-0 value is a safe wave-uniform scale proxy
            float m0 = __shfl(av, 0, 64);
            int e = ((__float_as_int(m0) >> 23) & 0xff) - 126;
            av = ldexpf(av, -e);
            etot += e;
          }
        }
        sh[(t & 1) * 64 + lane] = av;  // publish a_t (or re-publish frozen a)
      }
    }

    float ssum = wave_sum64(av);
    if (lane == 0)
      ws[b] = __logf(ssum) + (float)etot * 0.69314718055994530942f;

  } else {
    // ---------------- sequence score: unary + transition gathers ----------------
    const int b = blk - BB;
    const int L = seqlen[b];
    for (int i = lane; i < 4096; i += 64) sh[i] = K[i];
    __syncthreads();

    const int* tg = tags + b * TT;
    const float* pbase = pot + (size_t)b * TT * NN;
    float acc = 0.0f;
    for (int t = lane; t < TT; t += 64) {
      if (t < L) {
        int c = tg[t];
        float u = pbase[(size_t)t * 64 + c];
        float tr = 0.0f;
        if (t >= 1) {
          int p = tg[t - 1];
          tr = sh[p * 64 + c];
        }
        acc += u + tr;
      }
    }
    acc = wave_sum64(acc);
    if (lane == 0) ws[BB + b] = acc;
  }
}

__global__ __launch_bounds__(128) void crf_combine(
    const float* __restrict__ ws, const float* __restrict__ w,
    float* __restrict__ out) {
  const int i = threadIdx.x;  // 0..127
  float loss = -(ws[BB + i] - ws[i]) * w[i];
  loss = wave_sum64(loss);
  __shared__ float p[2];
  if ((i & 63) == 0) p[i >> 6] = loss;
  __syncthreads();
  if (i == 0) out[0] = (p[0] + p[1]) * (1.0f / 128.0f);
}

extern "C" void kernel_launch(void* const* d_in, const int* in_sizes, int n_in,
                              void* d_out, int out_size, void* d_ws, size_t ws_size,
                              hipStream_t stream) {
  const float* pot    = (const float*)d_in[0];
  const int*   tags   = (const int*)d_in[1];
  const int*   seqlen = (const int*)d_in[2];
  const float* K      = (const float*)d_in[3];
  const float* w      = (const float*)d_in[4];
  float* ws = (float*)d_ws;

  crf_main<<<256, 64, 0, stream>>>(pot, tags, seqlen, K, ws);
  crf_combine<<<1, 128, 0, stream>>>(ws, w, (float*)d_out);
}

// Round 3
// 213.067 us; speedup vs baseline: 1.7341x; 1.7341x over previous
//
#include <hip/hip_runtime.h>
#include <math.h>

#define BB 128
#define TT 1024
#define NN 64
#define NCH 16            // chunks per batch
#define SCH 64            // steps per chunk
#define CSTR 144          // LDS bytes per H column (64*2 + 16 pad -> kills bank conflicts)

typedef __attribute__((ext_vector_type(4))) float f32x4;
typedef __attribute__((ext_vector_type(8))) short bf16x8;

__device__ __forceinline__ float wave_sum64(float v) {
#pragma unroll
  for (int o = 32; o > 0; o >>= 1) v += __shfl_xor(v, o, 64);
  return v;
}

// f32 -> bf16 round-to-nearest-even
__device__ __forceinline__ unsigned short f2bf(float x) {
  unsigned u = __float_as_uint(x);
  u += 0x7fffu + ((u >> 16) & 1u);
  return (unsigned short)(u >> 16);
}

// ============================ PHASE 1 + SCORE =============================
// grid = 2048 + 128 blocks x 64 threads.
//  blk < 2048 : chunk product for (b = blk>>4, c = blk&15):
//               H = (M_{t1}^T ... M_{t0}^T) * 2^-etot  (bf16), M_t = E o (1 (x) p_t)
//               stored dword-transposed: Hg[blk*2048 + w*64 + j] = cols 2w,2w+1 of row j
//  blk >= 2048: unary+binary sequence score for b = blk-2048 -> score[b]
__global__ __launch_bounds__(64, 2) void crf_phase1(
    const float* __restrict__ pot, const int* __restrict__ tags,
    const int* __restrict__ seqlen, const float* __restrict__ K,
    unsigned* __restrict__ Hg, int* __restrict__ Eexp, float* __restrict__ score) {
  __shared__ __align__(16) float sh[4096];
  const int lane = threadIdx.x;
  const int blk = blockIdx.x;

  if (blk < BB * NCH) {
    const int b = blk >> 4;
    const int c = blk & 15;
    const int L = seqlen[b];
    const int q = lane >> 4;
    const int lm = lane & 15;

    // A-frags: A = E^T, E = exp(K); lane holds A[16mt+lm][32kt+8q+j]
    bf16x8 Af[4][2];
#pragma unroll
    for (int mt = 0; mt < 4; mt++)
#pragma unroll
      for (int kt = 0; kt < 2; kt++) {
        bf16x8 t;
#pragma unroll
        for (int j = 0; j < 8; j++)
          t[j] = (short)f2bf(__expf(K[(kt * 32 + q * 8 + j) * 64 + (mt * 16 + lm)]));
        Af[mt][kt] = t;
      }

    // init H = I (column-major, padded stride)
    unsigned short* Hs = (unsigned short*)sh;
    for (int i = lane; i < 2304; i += 64) sh[i] = 0.0f;
    Hs[lane * (CSTR / 2) + lane] = 0x3F80;  // H[k=lane][col=lane] = 1.0
    float* shp = sh + 2304;                 // p broadcast buffer (64 floats)

    int etot = 0;
    const int t0 = c * SCH + 1;
    const int tend = (L < TT) ? L : TT;  // execute while t < tend
    const float* pb = pot + (size_t)b * TT * NN + lane;

    float pf[4];
#pragma unroll
    for (int k = 0; k < 4; k++) {
      int tt = t0 + k; tt = tt > TT - 1 ? TT - 1 : tt;
      pf[k] = pb[(size_t)tt * NN];
    }

    for (int s = 0; s < SCH; s++) {
      const int t = t0 + s;
      if (t >= tend) break;  // wave-uniform

      float p = __expf(pf[s & 3]);
      int tn = t + 4; tn = tn > TT - 1 ? TT - 1 : tn;
      pf[s & 3] = pb[(size_t)tn * NN];
      shp[lane] = p;

      // lagged renorm proxy: previous H[0][0] (broadcast read)
      unsigned short hv = Hs[0];
      int e = ((hv >> 7) & 0xff) - 127;
      if ((hv & 0x7f80u) == 0) e = 0;

      // B-frags: B = H; lane holds H[32kt+8q+j][16nt+lm]
      bf16x8 Bf[2][4];
#pragma unroll
      for (int nt = 0; nt < 4; nt++)
#pragma unroll
        for (int kt = 0; kt < 2; kt++)
          Bf[kt][nt] = *(const bf16x8*)((const char*)sh +
                        (nt * 16 + lm) * CSTR + kt * 64 + q * 16);

      f32x4 D[4][4];
#pragma unroll
      for (int mt = 0; mt < 4; mt++)
#pragma unroll
        for (int nt = 0; nt < 4; nt++) {
          f32x4 d = {0.f, 0.f, 0.f, 0.f};
          d = __builtin_amdgcn_mfma_f32_16x16x32_bf16(Af[mt][0], Bf[0][nt], d, 0, 0, 0);
          d = __builtin_amdgcn_mfma_f32_16x16x32_bf16(Af[mt][1], Bf[1][nt], d, 0, 0, 0);
          D[mt][nt] = d;
        }

      // rows j of D scaled by p[j]*2^-e, pack bf16, write col-major (b64s)
      const float sc = ldexpf(1.0f, -e);
#pragma unroll
      for (int mt = 0; mt < 4; mt++) {
        float4 pt = *(const float4*)(shp + mt * 16 + q * 4);  // quad-broadcast
        float s0 = pt.x * sc, s1 = pt.y * sc, s2 = pt.z * sc, s3 = pt.w * sc;
#pragma unroll
        for (int nt = 0; nt < 4; nt++) {
          f32x4 d = D[mt][nt];
          uint2 wv;
          wv.x = (unsigned)f2bf(d[0] * s0) | ((unsigned)f2bf(d[1] * s1) << 16);
          wv.y = (unsigned)f2bf(d[2] * s2) | ((unsigned)f2bf(d[3] * s3) << 16);
          *(uint2*)((char*)sh + (nt * 16 + lm) * CSTR + (mt * 16 + q * 4) * 2) = wv;
        }
      }
      etot += e;
    }

    // transpose out: lane j emits row j of H as 32 dwords (cols 2w,2w+1)
    unsigned rw[32];
#pragma unroll
    for (int w2 = 0; w2 < 32; w2++) {
      unsigned short a0 = *(const unsigned short*)((const char*)sh + (2 * w2) * CSTR + lane * 2);
      unsigned short a1 = *(const unsigned short*)((const char*)sh + (2 * w2 + 1) * CSTR + lane * 2);
      rw[w2] = (unsigned)a0 | ((unsigned)a1 << 16);
    }
    unsigned* Hc = Hg + (size_t)blk * 2048;
#pragma unroll
    for (int w2 = 0; w2 < 32; w2++) Hc[w2 * 64 + lane] = rw[w2];  // coalesced
    if (lane == 0) Eexp[blk] = etot;

  } else {
    // ---------------- sequence score (validated in R1) ----------------
    const int b = blk - BB * NCH;
    const int L = seqlen[b];
    for (int i = lane; i < 4096; i += 64) sh[i] = K[i];
    __syncthreads();
    const int* tg = tags + b * TT;
    const float* pbase = pot + (size_t)b * TT * NN;
    float acc = 0.0f;
    for (int t = lane; t < TT; t += 64) {
      if (t < L) {
        int cc = tg[t];
        float u = pbase[(size_t)t * 64 + cc];
        float tr = 0.0f;
        if (t >= 1) tr = sh[tg[t - 1] * 64 + cc];
        acc += u + tr;
      }
    }
    acc = wave_sum64(acc);
    if (lane == 0) score[b] = acc;
  }
}

// ============================ PHASE 2 =============================
// 128 blocks x 64: block b applies its 16 chunk products to a (lane = state j)
__global__ __launch_bounds__(64, 2) void crf_phase2(
    const float* __restrict__ pot, const int* __restrict__ seqlen,
    const unsigned* __restrict__ Hg, const int* __restrict__ Eexp,
    const float* __restrict__ score, const float* __restrict__ wgt,
    float* __restrict__ loss) {
  __shared__ __align__(16) float sha[64];
  const int lane = threadIdx.x;
  const int b = blockIdx.x;

  float a = __expf(pot[(size_t)b * TT * NN + lane]);
  int atot = 0;
  sha[lane] = a;

  const unsigned* Hb = Hg + (size_t)b * NCH * 2048;
  unsigned rw[32], nx[32];
#pragma unroll
  for (int w2 = 0; w2 < 32; w2++) rw[w2] = Hb[w2 * 64 + lane];

  for (int c = 0; c < NCH; c++) {
    if (c + 1 < NCH) {
      const unsigned* Hn = Hb + (size_t)(c + 1) * 2048;
#pragma unroll
      for (int w2 = 0; w2 < 32; w2++) nx[w2] = Hn[w2 * 64 + lane];
    }
    const int ec = Eexp[b * NCH + c];
    float a00 = sha[0];  // lagged renorm proxy
    float S = 0.f;
#pragma unroll
    for (int g = 0; g < 16; g++) {
      float4 av = ((const float4*)sha)[g];
      unsigned r0 = rw[2 * g], r1 = rw[2 * g + 1];
      S += __uint_as_float(r0 << 16) * av.x + __uint_as_float(r0 & 0xffff0000u) * av.y;
      S += __uint_as_float(r1 << 16) * av.z + __uint_as_float(r1 & 0xffff0000u) * av.w;
    }
    unsigned ub = __float_as_uint(a00);
    int e2 = (int)((ub >> 23) & 0xff) - 127;
    if ((ub & 0x7f800000u) == 0) e2 = 0;
    a = ldexpf(S, -e2);
    atot += e2 + ec;
    sha[lane] = a;
    if (c + 1 < NCH) {
#pragma unroll
      for (int w2 = 0; w2 < 32; w2++) rw[w2] = nx[w2];
    }
  }

  float ssum = wave_sum64(a);
  if (lane == 0) {
    float lognorm = __logf(ssum) + (float)atot * 0.69314718055994530942f;
    loss[b] = -(score[b] - lognorm) * wgt[b];
  }
}

__global__ __launch_bounds__(128) void crf_reduce(
    const float* __restrict__ loss, float* __restrict__ out) {
  const int i = threadIdx.x;
  float v = loss[i];
  v = wave_sum64(v);
  __shared__ float p[2];
  if ((i & 63) == 0) p[i >> 6] = v;
  __syncthreads();
  if (i == 0) out[0] = (p[0] + p[1]) * (1.0f / 128.0f);
}

// ===================== R1 fallback (ws too small) =====================
__global__ __launch_bounds__(64) void crf_main_fb(
    const float* __restrict__ pot, const int* __restrict__ tags,
    const int* __restrict__ seqlen, const float* __restrict__ K,
    float* __restrict__ ws) {
  __shared__ float sh[4096];
  const int lane = threadIdx.x;
  const int blk = blockIdx.x;
  if (blk < BB) {
    const int b = blk;
    const int L = seqlen[b];
    float Ec[64];
#pragma unroll
    for (int i = 0; i < 64; i++) Ec[i] = __expf(K[i * 64 + lane]);
    const float* pb = pot + (size_t)b * TT * NN + lane;
    float av = __expf(pb[0]);
    int etot = 0;
    sh[lane] = av;
    float pf[8];
#pragma unroll
    for (int k = 0; k < 8; k++) pf[k] = pb[(size_t)(1 + k) * 64];
    for (int t0 = 1; t0 < L; t0 += 8) {
#pragma unroll
      for (int k = 0; k < 8; k++) {
        const int t = t0 + k;
        const float pe = __expf(pf[k]);
        int tn = t + 8; tn = tn > (TT - 1) ? (TT - 1) : tn;
        pf[k] = pb[(size_t)tn * 64];
        const float4* arow = (const float4*)(sh + ((t - 1) & 1) * 64);
        float s[8];
#pragma unroll
        for (int qq = 0; qq < 8; qq++) s[qq] = 0.0f;
#pragma unroll
        for (int qq = 0; qq < 16; qq++) {
          float4 a4 = arow[qq];
          float pr = fmaf(a4.x, Ec[4 * qq + 0], fmaf(a4.y, Ec[4 * qq + 1],
                     fmaf(a4.z, Ec[4 * qq + 2], a4.w * Ec[4 * qq + 3])));
          s[qq & 7] += pr;
        }
        float S = ((s[0] + s[1]) + (s[2] + s[3])) + ((s[4] + s[5]) + (s[6] + s[7]));
        if (t < L) {
          av = S * pe;
          if ((t & 3) == 0) {
            float m0 = __shfl(av, 0, 64);
            int e = ((__float_as_int(m0) >> 23) & 0xff) - 126;
            av = ldexpf(av, -e);
            etot += e;
          }
        }
        sh[(t & 1) * 64 + lane] = av;
      }
    }
    float ssum = wave_sum64(av);
    if (lane == 0) ws[b] = __logf(ssum) + (float)etot * 0.69314718055994530942f;
  } else {
    const int b = blk - BB;
    const int L = seqlen[b];
    for (int i = lane; i < 4096; i += 64) sh[i] = K[i];
    __syncthreads();
    const int* tg = tags + b * TT;
    const float* pbase = pot + (size_t)b * TT * NN;
    float acc = 0.0f;
    for (int t = lane; t < TT; t += 64) {
      if (t < L) {
        int cc = tg[t];
        float u = pbase[(size_t)t * 64 + cc];
        float tr = 0.0f;
        if (t >= 1) tr = sh[tg[t - 1] * 64 + cc];
        acc += u + tr;
      }
    }
    acc = wave_sum64(acc);
    if (lane == 0) ws[BB + b] = acc;
  }
}

__global__ __launch_bounds__(128) void crf_combine_fb(
    const float* __restrict__ ws, const float* __restrict__ wgt,
    float* __restrict__ out) {
  const int i = threadIdx.x;
  float lv = -(ws[BB + i] - ws[i]) * wgt[i];
  lv = wave_sum64(lv);
  __shared__ float p[2];
  if ((i & 63) == 0) p[i >> 6] = lv;
  __syncthreads();
  if (i == 0) out[0] = (p[0] + p[1]) * (1.0f / 128.0f);
}

extern "C" void kernel_launch(void* const* d_in, const int* in_sizes, int n_in,
                              void* d_out, int out_size, void* d_ws, size_t ws_size,
                              hipStream_t stream) {
  const float* pot    = (const float*)d_in[0];
  const int*   tags   = (const int*)d_in[1];
  const int*   seqlen = (const int*)d_in[2];
  const float* K      = (const float*)d_in[3];
  const float* wgt    = (const float*)d_in[4];

  const size_t HG_DW = (size_t)BB * NCH * 2048;  // 4,194,304 dwords = 16 MB
  const size_t need = (HG_DW + BB * NCH + BB + BB) * 4;

  if (ws_size >= need) {
    unsigned* Hg  = (unsigned*)d_ws;
    int* Eexp     = (int*)(Hg + HG_DW);
    float* score  = (float*)(Eexp + BB * NCH);
    float* loss   = score + BB;
    crf_phase1<<<BB * NCH + BB, 64, 0, stream>>>(pot, tags, seqlen, K, Hg, Eexp, score);
    crf_phase2<<<BB, 64, 0, stream>>>(pot, seqlen, Hg, Eexp, score, wgt, loss);
    crf_reduce<<<1, 128, 0, stream>>>(loss, (float*)d_out);
  } else {
    float* ws = (float*)d_ws;
    crf_main_fb<<<256, 64, 0, stream>>>(pot, tags, seqlen, K, ws);
    crf_combine_fb<<<1, 128, 0, stream>>>(ws, wgt, (float*)d_out);
  }
}

// Round 4
// 201.918 us; speedup vs baseline: 1.8298x; 1.0552x over previous
//
#include <hip/hip_runtime.h>
#include <math.h>

#define BB 128
#define TT 1024
#define NN 64
#define NCH 16            // chunks per batch
#define SCH 64            // steps per chunk
#define NG 2              // col-groups per chunk (32 cols each)

typedef __attribute__((ext_vector_type(4))) float f32x4;
typedef __attribute__((ext_vector_type(4))) short bf16x4;

__device__ __forceinline__ float wave_sum64(float v) {
#pragma unroll
  for (int o = 32; o > 0; o >>= 1) v += __shfl_xor(v, o, 64);
  return v;
}

// pack two positive f32 into a bf16-pair dword (round-half-up, 2 instr + perm)
__device__ __forceinline__ unsigned pkbf(float lo, float hi) {
  unsigned a = __float_as_uint(lo) + 0x8000u;
  unsigned b = __float_as_uint(hi) + 0x8000u;
  return __builtin_amdgcn_perm(b, a, 0x07060302u);  // {hi.b3,hi.b2,lo.b3,lo.b2}
}

__device__ __forceinline__ int fexp(float x) {  // unbiased exponent, 0 for denorm/zero
  unsigned u = __float_as_uint(x);
  int e = (int)((u >> 23) & 0xffu) - 127;
  if ((u & 0x7f800000u) == 0) e = 0;
  return e;
}

// ============================ PHASE 1 + SCORE =============================
// grid = 4096 + 128 blocks x 64 threads.
//  blk < 4096: chunk-product col-group: b = blk>>5, c = (blk>>1)&15, g = blk&1.
//    Evolves H-cols [32g,32g+32) of H = diag(p_last)·[E^T diag(p)]···E^T (bf16,
//    scaled 2^-etot) entirely in registers via 16x16x16 MFMA (D layout == B layout).
//    Out: Hg[(b*16+c)*2048 + (16g+w)*64 + j] = H[row j][cols 2w,2w+1] (bf16 pair).
//  blk >= 4096: unary+binary sequence score for b = blk-4096 (K via L1, no LDS).
__global__ __launch_bounds__(64, 4) void crf_phase1(
    const float* __restrict__ pot, const int* __restrict__ tags,
    const int* __restrict__ seqlen, const float* __restrict__ K,
    unsigned* __restrict__ Hg, int* __restrict__ Eexp, float* __restrict__ score,
    float* __restrict__ accf, unsigned* __restrict__ cnt) {
  __shared__ __align__(16) float shp[64];        // p_t broadcast
  __shared__ __align__(16) unsigned sht[32 * 33]; // chunk-end transpose buffer
  const int lane = threadIdx.x;
  const int blk = blockIdx.x;
  const int NSCAN = BB * NCH * NG;  // 4096

  if (blk < NSCAN) {
    const int b = blk >> 5;
    const int c = (blk >> 1) & 15;
    const int g = blk & 1;
    const int cg = g * 32;
    const int L = seqlen[b];
    const int q = lane >> 4, lm = lane & 15;

    const int t0 = c * SCH + 1;
    const int tend = (L < TT) ? L : TT;
    int nsteps = tend - t0;
    if (nsteps > SCH) nsteps = SCH;
    unsigned* Hc = Hg + (size_t)(b * NCH + c) * 2048 + g * 16 * 64;

    if (nsteps <= 0) {  // chunk fully past sequence end -> identity
#pragma unroll
      for (int w = 0; w < 16; w++) {
        int c0 = cg + 2 * w;
        unsigned v = (lane == c0 ? 0x3F80u : 0u) | (lane == c0 + 1 ? 0x3F800000u : 0u);
        Hc[w * 64 + lane] = v;
      }
      if (lane == 0) Eexp[(b * NCH + c) * NG + g] = 0;
      return;
    }

    // A-frags: A = E^T, A[m=mt*16+lm][k=kt*16+q*4+i] = exp(K[k*64+m])
    bf16x4 Af[4][4];
#pragma unroll
    for (int mt = 0; mt < 4; mt++)
#pragma unroll
      for (int kt = 0; kt < 4; kt++) {
        float v0 = __expf(K[(kt * 16 + q * 4 + 0) * 64 + mt * 16 + lm]);
        float v1 = __expf(K[(kt * 16 + q * 4 + 1) * 64 + mt * 16 + lm]);
        float v2 = __expf(K[(kt * 16 + q * 4 + 2) * 64 + mt * 16 + lm]);
        float v3 = __expf(K[(kt * 16 + q * 4 + 3) * 64 + mt * 16 + lm]);
        uint2 u; u.x = pkbf(v0, v1); u.y = pkbf(v2, v3);
        Af[mt][kt] = *(bf16x4*)&u;
      }

    // D_init = E^T (fp32): D[mt][nt][r] = E^T[mt*16+q*4+r][cg+nt*16+lm]
    f32x4 D[4][2];
#pragma unroll
    for (int mt = 0; mt < 4; mt++)
#pragma unroll
      for (int nt = 0; nt < 2; nt++) {
        f32x4 d;
#pragma unroll
        for (int r = 0; r < 4; r++)
          d[r] = __expf(K[(cg + nt * 16 + lm) * 64 + mt * 16 + q * 4 + r]);
        D[mt][nt] = d;
      }

    const float* pb = pot + (size_t)b * TT * NN + lane;
    float pf[4];
#pragma unroll
    for (int k = 0; k < 4; k++) {
      int tt = t0 + k; tt = tt > TT - 1 ? TT - 1 : tt;
      pf[k] = pb[(size_t)tt * NN];
    }
    int etot = 0;

    for (int s = 0; s < nsteps; s++) {
      float p = __expf(pf[s & 3]);
      int tn = t0 + s + 4; tn = tn > TT - 1 ? TT - 1 : tn;
      pf[s & 3] = pb[(size_t)tn * NN];
      shp[lane] = p;  // same-wave DS ordering guarantees read-after-write

      f32x4 pt[4];
#pragma unroll
      for (int kt = 0; kt < 4; kt++)
        pt[kt] = *(const f32x4*)(shp + kt * 16 + q * 4);

      if (s == nsteps - 1) {
        // epilogue: H = D ⊙ p_last (row-wise), renorm, transpose out via LDS
        float hf00 = __int_as_float(
            __builtin_amdgcn_readfirstlane(__float_as_int(D[0][0][0] * pt[0][0])));
        int ef = fexp(hf00);
        float sc = ldexpf(1.0f, -ef);
        etot += ef;
#pragma unroll
        for (int mt = 0; mt < 4; mt++)
#pragma unroll
          for (int nt = 0; nt < 2; nt++) {
            f32x4 d = D[mt][nt]; f32x4 pv = pt[mt];
            int base = (nt * 16 + lm) * 33 + mt * 8 + q * 2;
            sht[base]     = pkbf(d[0] * pv[0] * sc, d[1] * pv[1] * sc);
            sht[base + 1] = pkbf(d[2] * pv[2] * sc, d[3] * pv[3] * sc);
          }
        break;  // wave-uniform
      }

      float psc = 1.0f;
      if ((s & 7) == 7) {  // periodic exact power-of-2 renorm (growth ~2^7/step)
        float d00 = __int_as_float(
            __builtin_amdgcn_readfirstlane(__float_as_int(D[0][0][0])));
        int e = fexp(d00);
        psc = ldexpf(1.0f, -e);
        etot += e;
      }

      // B[kt][nt] = pack(p ⊙ D[kt][nt]) — D layout == B layout, no data movement
      bf16x4 Bf[4][2];
#pragma unroll
      for (int kt = 0; kt < 4; kt++) {
        f32x4 pv = pt[kt];
        float s0 = pv[0] * psc, s1 = pv[1] * psc, s2 = pv[2] * psc, s3 = pv[3] * psc;
#pragma unroll
        for (int nt = 0; nt < 2; nt++) {
          f32x4 d = D[kt][nt];
          uint2 u;
          u.x = pkbf(d[0] * s0, d[1] * s1);
          u.y = pkbf(d[2] * s2, d[3] * s3);
          Bf[kt][nt] = *(bf16x4*)&u;
        }
      }
      // D = A · B  (E^T · H)
#pragma unroll
      for (int mt = 0; mt < 4; mt++)
#pragma unroll
        for (int nt = 0; nt < 2; nt++) {
          f32x4 acc = {0.f, 0.f, 0.f, 0.f};
#pragma unroll
          for (int kt = 0; kt < 4; kt++)
            acc = __builtin_amdgcn_mfma_f32_16x16x16bf16_1k(Af[mt][kt], Bf[kt][nt], acc, 0, 0, 0);
          D[mt][nt] = acc;
        }
    }

    // transposed read-out: lane j = row; dword w = local cols 2w,2w+1
#pragma unroll
    for (int w = 0; w < 16; w++) {
      unsigned short a0 = ((const unsigned short*)(sht + (2 * w) * 33 + (lane >> 1)))[lane & 1];
      unsigned short a1 = ((const unsigned short*)(sht + (2 * w + 1) * 33 + (lane >> 1)))[lane & 1];
      Hc[w * 64 + lane] = (unsigned)a0 | ((unsigned)a1 << 16);
    }
    if (lane == 0) Eexp[(b * NCH + c) * NG + g] = etot;

  } else {
    // ---------------- sequence score (K via L1/L2, no LDS) ----------------
    const int b = blk - NSCAN;
    const int L = seqlen[b];
    if (blk == NSCAN && lane == 0) { *accf = 0.0f; *cnt = 0u; }  // zero atomic slots
    const int* tg = tags + b * TT;
    const float* pbase = pot + (size_t)b * TT * NN;
    float acc = 0.0f;
    for (int t = lane; t < TT; t += 64) {
      if (t < L) {
        int cc = tg[t];
        float u = pbase[(size_t)t * 64 + cc];
        float tr = (t >= 1) ? K[tg[t - 1] * 64 + cc] : 0.0f;
        acc += u + tr;
      }
    }
    acc = wave_sum64(acc);
    if (lane == 0) score[b] = acc;
  }
}

// ============================ PHASE 2 + REDUCE =============================
// 128 blocks x 64: block b applies its 16 chunk products; atomic-tail reduction.
__global__ __launch_bounds__(64, 2) void crf_phase2(
    const float* __restrict__ pot, const unsigned* __restrict__ Hg,
    const int* __restrict__ Eexp, const float* __restrict__ score,
    const float* __restrict__ wgt, float* __restrict__ accf,
    unsigned* __restrict__ cnt, float* __restrict__ out) {
  __shared__ __align__(16) float sha[64];
  const int lane = threadIdx.x;
  const int b = blockIdx.x;

  float a = __expf(pot[(size_t)b * TT * NN + lane]);
  int atot = 0;
  sha[lane] = a;

  const unsigned* Hb = Hg + (size_t)b * NCH * 2048;
  unsigned rw[32], nx[32];
#pragma unroll
  for (int w2 = 0; w2 < 32; w2++) rw[w2] = Hb[w2 * 64 + lane];

  for (int c = 0; c < NCH; c++) {
    if (c + 1 < NCH) {
      const unsigned* Hn = Hb + (size_t)(c + 1) * 2048;
#pragma unroll
      for (int w2 = 0; w2 < 32; w2++) nx[w2] = Hn[w2 * 64 + lane];
    }
    const int ec0 = Eexp[(b * NCH + c) * NG + 0];
    const int ec1 = Eexp[(b * NCH + c) * NG + 1];
    float a00 = sha[0];  // lagged renorm proxy
    float S0 = 0.f, S1 = 0.f;
#pragma unroll
    for (int g = 0; g < 8; g++) {
      float4 av = ((const float4*)sha)[g];
      unsigned r0 = rw[2 * g], r1 = rw[2 * g + 1];
      S0 += __uint_as_float(r0 << 16) * av.x + __uint_as_float(r0 & 0xffff0000u) * av.y;
      S0 += __uint_as_float(r1 << 16) * av.z + __uint_as_float(r1 & 0xffff0000u) * av.w;
    }
#pragma unroll
    for (int g = 8; g < 16; g++) {
      float4 av = ((const float4*)sha)[g];
      unsigned r0 = rw[2 * g], r1 = rw[2 * g + 1];
      S1 += __uint_as_float(r0 << 16) * av.x + __uint_as_float(r0 & 0xffff0000u) * av.y;
      S1 += __uint_as_float(r1 << 16) * av.z + __uint_as_float(r1 & 0xffff0000u) * av.w;
    }
    int em = ec0 > ec1 ? ec0 : ec1;
    int e2 = fexp(a00);
    a = ldexpf(ldexpf(S0, ec0 - em) + ldexpf(S1, ec1 - em), -e2);
    atot += e2 + em;
    sha[lane] = a;
    if (c + 1 < NCH) {
#pragma unroll
      for (int w2 = 0; w2 < 32; w2++) rw[w2] = nx[w2];
    }
  }

  float ssum = wave_sum64(a);
  if (lane == 0) {
    float lognorm = __logf(ssum) + (float)atot * 0.69314718055994530942f;
    float loss = -(score[b] - lognorm) * wgt[b];
    atomicAdd(accf, loss * (1.0f / BB));
    __threadfence();
    unsigned old = atomicAdd(cnt, 1u);
    if (old == BB - 1) out[0] = atomicAdd(accf, 0.0f);  // coherent read of full sum
  }
}

// ===================== R1 fallback (ws too small) =====================
__global__ __launch_bounds__(64) void crf_main_fb(
    const float* __restrict__ pot, const int* __restrict__ tags,
    const int* __restrict__ seqlen, const float* __restrict__ K,
    float* __restrict__ ws) {
  __shared__ float sh[4096];
  const int lane = threadIdx.x;
  const int blk = blockIdx.x;
  if (blk < BB) {
    const int b = blk;
    const int L = seqlen[b];
    float Ec[64];
#pragma unroll
    for (int i = 0; i < 64; i++) Ec[i] = __expf(K[i * 64 + lane]);
    const float* pb = pot + (size_t)b * TT * NN + lane;
    float av = __expf(pb[0]);
    int etot = 0;
    sh[lane] = av;
    float pf[8];
#pragma unroll
    for (int k = 0; k < 8; k++) pf[k] = pb[(size_t)(1 + k) * 64];
    for (int t0 = 1; t0 < L; t0 += 8) {
#pragma unroll
      for (int k = 0; k < 8; k++) {
        const int t = t0 + k;
        const float pe = __expf(pf[k]);
        int tn = t + 8; tn = tn > (TT - 1) ? (TT - 1) : tn;
        pf[k] = pb[(size_t)tn * 64];
        const float4* arow = (const float4*)(sh + ((t - 1) & 1) * 64);
        float s[8];
#pragma unroll
        for (int qq = 0; qq < 8; qq++) s[qq] = 0.0f;
#pragma unroll
        for (int qq = 0; qq < 16; qq++) {
          float4 a4 = arow[qq];
          float pr = fmaf(a4.x, Ec[4 * qq + 0], fmaf(a4.y, Ec[4 * qq + 1],
                     fmaf(a4.z, Ec[4 * qq + 2], a4.w * Ec[4 * qq + 3])));
          s[qq & 7] += pr;
        }
        float S = ((s[0] + s[1]) + (s[2] + s[3])) + ((s[4] + s[5]) + (s[6] + s[7]));
        if (t < L) {
          av = S * pe;
          if ((t & 3) == 0) {
            float m0 = __shfl(av, 0, 64);
            int e = ((__float_as_int(m0) >> 23) & 0xff) - 126;
            av = ldexpf(av, -e);
            etot += e;
          }
        }
        sh[(t & 1) * 64 + lane] = av;
      }
    }
    float ssum = wave_sum64(av);
    if (lane == 0) ws[b] = __logf(ssum) + (float)etot * 0.69314718055994530942f;
  } else {
    const int b = blk - BB;
    const int L = seqlen[b];
    for (int i = lane; i < 4096; i += 64) sh[i] = K[i];
    __syncthreads();
    const int* tg = tags + b * TT;
    const float* pbase = pot + (size_t)b * TT * NN;
    float acc = 0.0f;
    for (int t = lane; t < TT; t += 64) {
      if (t < L) {
        int cc = tg[t];
        float u = pbase[(size_t)t * 64 + cc];
        float tr = 0.0f;
        if (t >= 1) tr = sh[tg[t - 1] * 64 + cc];
        acc += u + tr;
      }
    }
    acc = wave_sum64(acc);
    if (lane == 0) ws[BB + b] = acc;
  }
}

__global__ __launch_bounds__(128) void crf_combine_fb(
    const float* __restrict__ ws, const float* __restrict__ wgt,
    float* __restrict__ out) {
  const int i = threadIdx.x;
  float lv = -(ws[BB + i] - ws[i]) * wgt[i];
  lv = wave_sum64(lv);
  __shared__ float p[2];
  if ((i & 63) == 0) p[i >> 6] = lv;
  __syncthreads();
  if (i == 0) out[0] = (p[0] + p[1]) * (1.0f / 128.0f);
}

extern "C" void kernel_launch(void* const* d_in, const int* in_sizes, int n_in,
                              void* d_out, int out_size, void* d_ws, size_t ws_size,
                              hipStream_t stream) {
  const float* pot    = (const float*)d_in[0];
  const int*   tags   = (const int*)d_in[1];
  const int*   seqlen = (const int*)d_in[2];
  const float* K      = (const float*)d_in[3];
  const float* wgt    = (const float*)d_in[4];

  const size_t HG_DW = (size_t)BB * NCH * 2048;  // 16 MB of bf16-pair dwords
  const size_t NEXP  = (size_t)BB * NCH * NG;
  const size_t need  = (HG_DW + NEXP + BB + 2) * 4;

  if (ws_size >= need) {
    unsigned* Hg    = (unsigned*)d_ws;
    int* Eexp       = (int*)(Hg + HG_DW);
    float* score    = (float*)(Eexp + NEXP);
    float* accf     = score + BB;
    unsigned* cntp  = (unsigned*)(accf + 1);
    crf_phase1<<<BB * NCH * NG + BB, 64, 0, stream>>>(pot, tags, seqlen, K, Hg, Eexp,
                                                      score, accf, cntp);
    crf_phase2<<<BB, 64, 0, stream>>>(pot, Hg, Eexp, score, wgt, accf, cntp,
                                      (float*)d_out);
  } else {
    float* ws = (float*)d_ws;
    crf_main_fb<<<256, 64, 0, stream>>>(pot, tags, seqlen, K, ws);
    crf_combine_fb<<<1, 128, 0, stream>>>(ws, wgt, (float*)d_out);
  }
}

// Round 5
// 185.720 us; speedup vs baseline: 1.9894x; 1.0872x over previous
//
#include <hip/hip_runtime.h>
#include <math.h>

#define BB 128
#define TT 1024
#define NN 64
#define NCH 16              // chunks per batch
#define SCH 64              // steps per chunk
#define NSCORE 64           // score blocks (2 batches each)
#define NSC (BB * NCH * 2)  // scan blocks: 4096 (2 col-group waves each)

typedef __attribute__((ext_vector_type(4))) float f32x4;
typedef __attribute__((ext_vector_type(4))) short bf16x4;

__device__ __forceinline__ float wave_sum64(float v) {
#pragma unroll
  for (int o = 32; o > 0; o >>= 1) v += __shfl_xor(v, o, 64);
  return v;
}

// pack two positive f32 into a bf16-pair dword (round-half-up)
__device__ __forceinline__ unsigned pkbf(float lo, float hi) {
  unsigned a = __float_as_uint(lo) + 0x8000u;
  unsigned b = __float_as_uint(hi) + 0x8000u;
  return __builtin_amdgcn_perm(b, a, 0x07060302u);
}

__device__ __forceinline__ int fexp(float x) {  // unbiased exponent, 0 for denorm/zero
  unsigned u = __float_as_uint(x);
  int e = (int)((u >> 23) & 0xffu) - 127;
  if ((u & 0x7f800000u) == 0) e = 0;
  return e;
}

// ============================ PHASE 1 + SCORE =============================
// grid = 64 + 4096 blocks x 128 threads (2 waves).
//  blk <  64 : sequence score, wave w handles batch b = blk*2+w.
//  blk >= 64 : idx = blk-64; c = idx>>8 (high bits -> per-CU chunk balance),
//              b = (idx>>1)&127, col-group g = (idx&1)*2 + wave.
//    Wave evolves 16 cols [16g,16g+16) of H = diag(p_last)·[E^T diag(p)]···E^T
//    (bf16, scaled 2^-etot) fully in registers (16x16x16 MFMA: D layout == B layout).
//    Out: Hg[(b*16+c)*2048 + (8g+w)*64 + j] = H[row j][cols 16g+2w, 16g+2w+1].
__global__ __launch_bounds__(128, 4) void crf_phase1(
    const float* __restrict__ pot, const int* __restrict__ tags,
    const int* __restrict__ seqlen, const float* __restrict__ K,
    unsigned* __restrict__ Hg, int* __restrict__ Eexp, float* __restrict__ score,
    float* __restrict__ accf, unsigned* __restrict__ cnt) {
  __shared__ __align__(16) unsigned sht[2][544];  // per-wave transpose buffer
  const int tid = threadIdx.x;
  const int wv = tid >> 6;
  const int lane = tid & 63;
  const int blk = blockIdx.x;

  if (blk == 0 && tid == 0) { *accf = 0.0f; *cnt = 0u; }  // zero atomic slots

  if (blk < NSCORE) {
    // ---------------- sequence score (K via L1/L2, no LDS) ----------------
    const int b = blk * 2 + wv;
    const int L = seqlen[b];
    const int* tg = tags + b * TT;
    const float* pbase = pot + (size_t)b * TT * NN;
    float acc = 0.0f;
    for (int t = lane; t < TT; t += 64) {
      if (t < L) {
        int cc = tg[t];
        float u = pbase[(size_t)t * 64 + cc];
        float tr = (t >= 1) ? K[tg[t - 1] * 64 + cc] : 0.0f;
        acc += u + tr;
      }
    }
    acc = wave_sum64(acc);
    if (lane == 0) score[b] = acc;
    return;
  }

  const int idx = blk - NSCORE;
  const int c = idx >> 8;                     // chunk index in HIGH bits (balance)
  const int b = (idx >> 1) & (BB - 1);
  const int g = ((idx & 1) << 1) | wv;        // col-group 0..3
  const int L = seqlen[b];
  const int q = lane >> 4, lm = lane & 15;

  const int t0 = c * SCH + 1;
  const int tend = (L < TT) ? L : TT;
  int nsteps = tend - t0;
  if (nsteps > SCH) nsteps = SCH;

  unsigned* Hc = Hg + (size_t)(b * NCH + c) * 2048 + g * 8 * 64;
  if (nsteps <= 0) {  // chunk fully past sequence end -> identity block
#pragma unroll
    for (int w = 0; w < 8; w++) {
      int c0 = g * 16 + 2 * w;
      unsigned v = (lane == c0 ? 0x3F80u : 0u) | (lane == c0 + 1 ? 0x3F800000u : 0u);
      Hc[w * 64 + lane] = v;
    }
    if (lane == 0) Eexp[(b * NCH + c) * 4 + g] = 0;
    return;
  }

  // A-frags: A = E^T, A[m=16mt+lm][k=16kt+4q+i] = exp(K[k*64+m])
  bf16x4 Af[4][4];
#pragma unroll
  for (int mt = 0; mt < 4; mt++)
#pragma unroll
    for (int kt = 0; kt < 4; kt++) {
      float v0 = __expf(K[(kt * 16 + q * 4 + 0) * 64 + mt * 16 + lm]);
      float v1 = __expf(K[(kt * 16 + q * 4 + 1) * 64 + mt * 16 + lm]);
      float v2 = __expf(K[(kt * 16 + q * 4 + 2) * 64 + mt * 16 + lm]);
      float v3 = __expf(K[(kt * 16 + q * 4 + 3) * 64 + mt * 16 + lm]);
      uint2 u; u.x = pkbf(v0, v1); u.y = pkbf(v2, v3);
      Af[mt][kt] = *(bf16x4*)&u;
    }

  // D_init = E^T: D[mt][r] = E^T[16mt+4q+r][16g+lm]
  f32x4 D[4];
#pragma unroll
  for (int mt = 0; mt < 4; mt++) {
    f32x4 d;
#pragma unroll
    for (int r = 0; r < 4; r++)
      d[r] = __expf(K[(g * 16 + lm) * 64 + mt * 16 + q * 4 + r]);
    D[mt] = d;
  }

  // p pipeline: direct global float4 loads of exactly the rows this lane packs
  // (rows 16kt+4q+0..3) — no LDS in the K-loop. raw = t+1 in flight, px = exp(p_t).
  const float* P = pot + (size_t)b * TT * NN + q * 4;
  f32x4 raw[4], px[4];
#pragma unroll
  for (int kt = 0; kt < 4; kt++) raw[kt] = *(const f32x4*)(P + (size_t)t0 * NN + kt * 16);
#pragma unroll
  for (int kt = 0; kt < 4; kt++) {
#pragma unroll
    for (int i = 0; i < 4; i++) px[kt][i] = __expf(raw[kt][i]);
  }
  {
    int t1 = t0 + 1 > TT - 1 ? TT - 1 : t0 + 1;
#pragma unroll
    for (int kt = 0; kt < 4; kt++) raw[kt] = *(const f32x4*)(P + (size_t)t1 * NN + kt * 16);
  }
  int etot = 0;

  for (int s = 0; s < nsteps - 1; s++) {
    float psc = 1.0f;
    if ((s & 7) == 7) {  // periodic exact power-of-2 renorm
      float d00 = __int_as_float(__builtin_amdgcn_readfirstlane(__float_as_int(D[0][0])));
      int e = fexp(d00);
      psc = ldexpf(1.0f, -e);
      etot += e;
    }
    // B[kt] = bf16(px ⊙ D[kt] ⊙ psc) — D layout == B layout
    bf16x4 Bf[4];
#pragma unroll
    for (int kt = 0; kt < 4; kt++) {
      f32x4 pv = px[kt];
      float s0 = pv[0] * psc, s1 = pv[1] * psc, s2 = pv[2] * psc, s3 = pv[3] * psc;
      f32x4 d = D[kt];
      uint2 u;
      u.x = pkbf(d[0] * s0, d[1] * s1);
      u.y = pkbf(d[2] * s2, d[3] * s3);
      Bf[kt] = *(bf16x4*)&u;
    }
    // px for step s+1 (raw landed; loaded one full step ago)
#pragma unroll
    for (int kt = 0; kt < 4; kt++) {
#pragma unroll
      for (int i = 0; i < 4; i++) px[kt][i] = __expf(raw[kt][i]);
    }
    // prefetch raw for step s+2
    {
      int tn = t0 + s + 2; tn = tn > TT - 1 ? TT - 1 : tn;
#pragma unroll
      for (int kt = 0; kt < 4; kt++) raw[kt] = *(const f32x4*)(P + (size_t)tn * NN + kt * 16);
    }
    // D = A · B  (E^T · diag(p) · H)
#pragma unroll
    for (int mt = 0; mt < 4; mt++) {
      f32x4 acc = {0.f, 0.f, 0.f, 0.f};
#pragma unroll
      for (int kt = 0; kt < 4; kt++)
        acc = __builtin_amdgcn_mfma_f32_16x16x16bf16_1k(Af[mt][kt], Bf[kt], acc, 0, 0, 0);
      D[mt] = acc;
    }
  }

  // epilogue: H = diag(p_last)·D, renorm, transpose out via per-wave LDS
  {
    float hf = __int_as_float(
        __builtin_amdgcn_readfirstlane(__float_as_int(D[0][0] * px[0][0])));
    int ef = fexp(hf);
    float sc = ldexpf(1.0f, -ef);
    etot += ef;
    unsigned* sw = sht[wv];
#pragma unroll
    for (int mt = 0; mt < 4; mt++) {
      f32x4 d = D[mt]; f32x4 pv = px[mt];
      int base = lm * 33 + mt * 8 + q * 2;
      sw[base]     = pkbf(d[0] * pv[0] * sc, d[1] * pv[1] * sc);
      sw[base + 1] = pkbf(d[2] * pv[2] * sc, d[3] * pv[3] * sc);
    }
#pragma unroll
    for (int w = 0; w < 8; w++) {
      unsigned short a0 = ((const unsigned short*)(sw + (2 * w) * 33 + (lane >> 1)))[lane & 1];
      unsigned short a1 = ((const unsigned short*)(sw + (2 * w + 1) * 33 + (lane >> 1)))[lane & 1];
      Hc[w * 64 + lane] = (unsigned)a0 | ((unsigned)a1 << 16);
    }
    if (lane == 0) Eexp[(b * NCH + c) * 4 + g] = etot;
  }
}

// ============================ PHASE 2 + REDUCE =============================
// 128 blocks x 256 threads: block b. Wave w computes partials over input rows
// [16w,16w+16) (== phase1 col-group w scales); wave 0 combines + renorms.
__global__ __launch_bounds__(256, 2) void crf_phase2(
    const float* __restrict__ pot, const unsigned* __restrict__ Hg,
    const int* __restrict__ Eexp, const float* __restrict__ score,
    const float* __restrict__ wgt, float* __restrict__ accf,
    unsigned* __restrict__ cnt, float* __restrict__ out) {
  __shared__ __align__(16) float sha[64];
  __shared__ float part[4][64];
  __shared__ int shE[64];
  const int tid = threadIdx.x;
  const int w = tid >> 6;
  const int j = tid & 63;
  const int b = blockIdx.x;

  if (w == 0) {
    sha[j] = __expf(pot[(size_t)b * TT * NN + j]);
    shE[j] = Eexp[b * 64 + j];  // (b*16+c)*4+g = b*64 + c*4 + g
  }
  const unsigned* Hb = Hg + (size_t)b * NCH * 2048 + (size_t)w * 8 * 64;
  unsigned rw[8], nx[8];
#pragma unroll
  for (int k = 0; k < 8; k++) rw[k] = Hb[k * 64 + j];
  __syncthreads();

  int atot = 0;
  float a = 0.0f;
  for (int c = 0; c < NCH; c++) {
    if (c + 1 < NCH) {
#pragma unroll
      for (int k = 0; k < 8; k++) nx[k] = Hb[(size_t)(c + 1) * 2048 + k * 64 + j];
    }
    // partial_w[j] = sum_{i in [16w,16w+16)} H[j][i] * a[i]
    float S = 0.0f;
#pragma unroll
    for (int k = 0; k < 8; k++) {
      float aLo = sha[16 * w + 2 * k], aHi = sha[16 * w + 2 * k + 1];
      S += __uint_as_float(rw[k] << 16) * aLo +
           __uint_as_float(rw[k] & 0xffff0000u) * aHi;
    }
    part[w][j] = S;
    __syncthreads();
    if (w == 0) {
      int e0 = shE[c * 4 + 0], e1 = shE[c * 4 + 1];
      int e2 = shE[c * 4 + 2], e3 = shE[c * 4 + 3];
      int em = max(max(e0, e1), max(e2, e3));
      float Sc = ldexpf(part[0][j], e0 - em) + ldexpf(part[1][j], e1 - em) +
                 ldexpf(part[2][j], e2 - em) + ldexpf(part[3][j], e3 - em);
      int er = fexp(__int_as_float(
          __builtin_amdgcn_readfirstlane(__float_as_int(Sc))));
      a = ldexpf(Sc, -er);
      sha[j] = a;
      atot += em + er;
    }
    __syncthreads();
#pragma unroll
    for (int k = 0; k < 8; k++) rw[k] = nx[k];
  }

  if (w == 0) {
    float ssum = wave_sum64(a);
    if (j == 0) {
      float lognorm = __logf(ssum) + (float)atot * 0.69314718055994530942f;
      float loss = -(score[b] - lognorm) * wgt[b];
      atomicAdd(accf, loss * (1.0f / BB));
      __threadfence();
      unsigned old = atomicAdd(cnt, 1u);
      if (old == BB - 1) out[0] = atomicAdd(accf, 0.0f);
    }
  }
}

// ===================== R1 fallback (ws too small) =====================
__global__ __launch_bounds__(64) void crf_main_fb(
    const float* __restrict__ pot, const int* __restrict__ tags,
    const int* __restrict__ seqlen, const float* __restrict__ K,
    float* __restrict__ ws) {
  __shared__ float sh[4096];
  const int lane = threadIdx.x;
  const int blk = blockIdx.x;
  if (blk < BB) {
    const int b = blk;
    const int L = seqlen[b];
    float Ec[64];
#pragma unroll
    for (int i = 0; i < 64; i++) Ec[i] = __expf(K[i * 64 + lane]);
    const float* pb = pot + (size_t)b * TT * NN + lane;
    float av = __expf(pb[0]);
    int etot = 0;
    sh[lane] = av;
    float pf[8];
#pragma unroll
    for (int k = 0; k < 8; k++) pf[k] = pb[(size_t)(1 + k) * 64];
    for (int t0 = 1; t0 < L; t0 += 8) {
#pragma unroll
      for (int k = 0; k < 8; k++) {
        const int t = t0 + k;
        const float pe = __expf(pf[k]);
        int tn = t + 8; tn = tn > (TT - 1) ? (TT - 1) : tn;
        pf[k] = pb[(size_t)tn * 64];
        const float4* arow = (const float4*)(sh + ((t - 1) & 1) * 64);
        float s[8];
#pragma unroll
        for (int qq = 0; qq < 8; qq++) s[qq] = 0.0f;
#pragma unroll
        for (int qq = 0; qq < 16; qq++) {
          float4 a4 = arow[qq];
          float pr = fmaf(a4.x, Ec[4 * qq + 0], fmaf(a4.y, Ec[4 * qq + 1],
                     fmaf(a4.z, Ec[4 * qq + 2], a4.w * Ec[4 * qq + 3])));
          s[qq & 7] += pr;
        }
        float S = ((s[0] + s[1]) + (s[2] + s[3])) + ((s[4] + s[5]) + (s[6] + s[7]));
        if (t < L) {
          av = S * pe;
          if ((t & 3) == 0) {
            float m0 = __shfl(av, 0, 64);
            int e = ((__float_as_int(m0) >> 23) & 0xff) - 126;
            av = ldexpf(av, -e);
            etot += e;
          }
        }
        sh[(t & 1) * 64 + lane] = av;
      }
    }
    float ssum = wave_sum64(av);
    if (lane == 0) ws[b] = __logf(ssum) + (float)etot * 0.69314718055994530942f;
  } else {
    const int b = blk - BB;
    const int L = seqlen[b];
    for (int i = lane; i < 4096; i += 64) sh[i] = K[i];
    __syncthreads();
    const int* tg = tags + b * TT;
    const float* pbase = pot + (size_t)b * TT * NN;
    float acc = 0.0f;
    for (int t = lane; t < TT; t += 64) {
      if (t < L) {
        int cc = tg[t];
        float u = pbase[(size_t)t * 64 + cc];
        float tr = 0.0f;
        if (t >= 1) tr = sh[tg[t - 1] * 64 + cc];
        acc += u + tr;
      }
    }
    acc = wave_sum64(acc);
    if (lane == 0) ws[BB + b] = acc;
  }
}

__global__ __launch_bounds__(128) void crf_combine_fb(
    const float* __restrict__ ws, const float* __restrict__ wgt,
    float* __restrict__ out) {
  const int i = threadIdx.x;
  float lv = -(ws[BB + i] - ws[i]) * wgt[i];
  lv = wave_sum64(lv);
  __shared__ float p[2];
  if ((i & 63) == 0) p[i >> 6] = lv;
  __syncthreads();
  if (i == 0) out[0] = (p[0] + p[1]) * (1.0f / 128.0f);
}

extern "C" void kernel_launch(void* const* d_in, const int* in_sizes, int n_in,
                              void* d_out, int out_size, void* d_ws, size_t ws_size,
                              hipStream_t stream) {
  const float* pot    = (const float*)d_in[0];
  const int*   tags   = (const int*)d_in[1];
  const int*   seqlen = (const int*)d_in[2];
  const float* K      = (const float*)d_in[3];
  const float* wgt    = (const float*)d_in[4];

  const size_t HG_DW = (size_t)BB * NCH * 2048;  // 16 MB of bf16-pair dwords
  const size_t NEXP  = (size_t)BB * NCH * 4;
  const size_t need  = (HG_DW + NEXP + BB + 2) * 4;

  if (ws_size >= need) {
    unsigned* Hg    = (unsigned*)d_ws;
    int* Eexp       = (int*)(Hg + HG_DW);
    float* score    = (float*)(Eexp + NEXP);
    float* accf     = score + BB;
    unsigned* cntp  = (unsigned*)(accf + 1);
    crf_phase1<<<NSC + NSCORE, 128, 0, stream>>>(pot, tags, seqlen, K, Hg, Eexp,
                                                 score, accf, cntp);
    crf_phase2<<<BB, 256, 0, stream>>>(pot, Hg, Eexp, score, wgt, accf, cntp,
                                       (float*)d_out);
  } else {
    float* ws = (float*)d_ws;
    crf_main_fb<<<256, 64, 0, stream>>>(pot, tags, seqlen, K, ws);
    crf_combine_fb<<<1, 128, 0, stream>>>(ws, wgt, (float*)d_out);
  }
}

// Round 6
// 171.238 us; speedup vs baseline: 2.1577x; 1.0846x over previous
//
#include <hip/hip_runtime.h>
#include <math.h>

#define BB 128
#define TT 1024
#define NN 64
#define NCH 16              // chunks per batch
#define SCH 64              // steps per chunk

typedef __attribute__((ext_vector_type(4))) float f32x4;
typedef __attribute__((ext_vector_type(4))) short bf16x4;

__device__ __forceinline__ float wave_sum64(float v) {
#pragma unroll
  for (int o = 32; o > 0; o >>= 1) v += __shfl_xor(v, o, 64);
  return v;
}

// pack two positive f32 into a bf16-pair dword (round-half-up)
__device__ __forceinline__ unsigned pkbf(float lo, float hi) {
  unsigned a = __float_as_uint(lo) + 0x8000u;
  unsigned b = __float_as_uint(hi) + 0x8000u;
  return __builtin_amdgcn_perm(b, a, 0x07060302u);
}

__device__ __forceinline__ int fexp(float x) {  // unbiased exponent, 0 for denorm/zero
  unsigned u = __float_as_uint(x);
  int e = (int)((u >> 23) & 0xffu) - 127;
  if ((u & 0x7f800000u) == 0) e = 0;
  return e;
}

// ============================ PHASE 1 + SCORE =============================
// grid = 128 + 8192 blocks x 64 threads (1 wave).
//  blk < 128 : sequence score for batch blk.
//  blk >= 128: idx = blk-128; c = idx>>9 (high bits -> per-CU chunk balance),
//              b = (idx>>2)&127, col-group g = idx&3.
//    Wave evolves 16 cols [16g,16g+16) of H = diag(p_last)·[E^T diag(p)]···E^T
//    (bf16, scaled 2^-etot) in registers (16x16x16 MFMA: D layout == B layout).
//    p = exp(pot) produced ONCE per step per wave (lane j owns row j) and
//    broadcast through a per-wave LDS ring — no barriers (same-wave DS order).
//    Out: Hg[(b*16+c)*2048 + (8g+w)*64 + j] = H[row j][cols 16g+2w, 16g+2w+1].
__global__ __launch_bounds__(64, 4) void crf_phase1(
    const float* __restrict__ pot, const int* __restrict__ tags,
    const int* __restrict__ seqlen, const float* __restrict__ K,
    unsigned* __restrict__ Hg, int* __restrict__ Eexp, float* __restrict__ score,
    float* __restrict__ accf, unsigned* __restrict__ cnt) {
  __shared__ __align__(16) float ring[4 * 64];   // px broadcast ring
  __shared__ __align__(16) unsigned sht[544];    // epilogue transpose buffer
  const int lane = threadIdx.x;
  const int blk = blockIdx.x;

  if (blk == 0 && lane == 0) { *accf = 0.0f; *cnt = 0u; }  // zero atomic slots

  if (blk < BB) {
    // ---------------- sequence score (K via L1/L2) ----------------
    const int b = blk;
    const int L = seqlen[b];
    const int* tg = tags + b * TT;
    const float* pbase = pot + (size_t)b * TT * NN;
    float acc = 0.0f;
    for (int t = lane; t < TT; t += 64) {
      if (t < L) {
        int cc = tg[t];
        float u = pbase[(size_t)t * 64 + cc];
        float tr = (t >= 1) ? K[tg[t - 1] * 64 + cc] : 0.0f;
        acc += u + tr;
      }
    }
    acc = wave_sum64(acc);
    if (lane == 0) score[b] = acc;
    return;
  }

  const int idx = blk - BB;
  const int c = idx >> 9;            // chunk index in HIGH bits (balance)
  const int b = (idx >> 2) & (BB - 1);
  const int g = idx & 3;             // col-group 0..3
  const int L = seqlen[b];
  const int q = lane >> 4, lm = lane & 15;
  const int rb = q * 4;              // this lane's base row within a 16-row k-tile

  const int t0 = c * SCH + 1;
  const int tend = (L < TT) ? L : TT;
  int nsteps = tend - t0;
  if (nsteps > SCH) nsteps = SCH;

  unsigned* Hc = Hg + (size_t)(b * NCH + c) * 2048 + g * 8 * 64;
  if (nsteps <= 0) {  // chunk fully past sequence end -> identity block
#pragma unroll
    for (int w = 0; w < 8; w++) {
      int c0 = g * 16 + 2 * w;
      unsigned v = (lane == c0 ? 0x3F80u : 0u) | (lane == c0 + 1 ? 0x3F800000u : 0u);
      Hc[w * 64 + lane] = v;
    }
    if (lane == 0) Eexp[(b * NCH + c) * 4 + g] = 0;
    return;
  }

  // A-frags: A = E^T, A[m=16mt+lm][k=16kt+4q+i] = exp(K[k*64+m])
  bf16x4 Af[4][4];
#pragma unroll
  for (int mt = 0; mt < 4; mt++)
#pragma unroll
    for (int kt = 0; kt < 4; kt++) {
      float v0 = __expf(K[(kt * 16 + rb + 0) * 64 + mt * 16 + lm]);
      float v1 = __expf(K[(kt * 16 + rb + 1) * 64 + mt * 16 + lm]);
      float v2 = __expf(K[(kt * 16 + rb + 2) * 64 + mt * 16 + lm]);
      float v3 = __expf(K[(kt * 16 + rb + 3) * 64 + mt * 16 + lm]);
      uint2 u; u.x = pkbf(v0, v1); u.y = pkbf(v2, v3);
      Af[mt][kt] = *(bf16x4*)&u;
    }

  // D_init = E^T: D[mt][r] = E^T[16mt+4q+r][16g+lm]
  f32x4 D[4];
#pragma unroll
  for (int mt = 0; mt < 4; mt++) {
    f32x4 d;
#pragma unroll
    for (int r = 0; r < 4; r++)
      d[r] = __expf(K[(g * 16 + lm) * 64 + mt * 16 + rb + r]);
    D[mt] = d;
  }

  // px pipeline: lane j produces exp(pot[t, j]) once; ring slots t mod 4.
  const float* Pj = pot + (size_t)b * TT * NN + lane;
#pragma unroll
  for (int k = 0; k < 3; k++) {  // slots 0..2 = px(t0..t0+2)
    int tt = t0 + k; tt = tt > TT - 1 ? TT - 1 : tt;
    ring[k * 64 + lane] = __expf(Pj[(size_t)tt * NN]);
  }
  int t3 = t0 + 3 > TT - 1 ? TT - 1 : t0 + 3;
  int t4 = t0 + 4 > TT - 1 ? TT - 1 : t0 + 4;
  float rawq0 = Pj[(size_t)t3 * NN];
  float rawq1 = Pj[(size_t)t4 * NN];

  f32x4 pxc[4], pxn[4];
#pragma unroll
  for (int kt = 0; kt < 4; kt++)
    pxc[kt] = *(const f32x4*)&ring[0 * 64 + kt * 16 + rb];

  int etot = 0;
#pragma unroll 2
  for (int s = 0; s < nsteps - 1; s++) {
    if ((s & 7) == 7) {  // periodic exact power-of-2 renorm, folded into pxc
      float d00 = __int_as_float(__builtin_amdgcn_readfirstlane(__float_as_int(D[0][0])));
      int e = fexp(d00);
      float psc = ldexpf(1.0f, -e);
      etot += e;
#pragma unroll
      for (int kt = 0; kt < 4; kt++) pxc[kt] *= psc;
    }
    // B[kt] = bf16(pxc ⊙ D[kt]) — D layout == B layout
    bf16x4 Bf[4];
#pragma unroll
    for (int kt = 0; kt < 4; kt++) {
      f32x4 pr = D[kt] * pxc[kt];
      uint2 u;
      u.x = pkbf(pr[0], pr[1]);
      u.y = pkbf(pr[2], pr[3]);
      Bf[kt] = *(bf16x4*)&u;
    }
    // read px(t+1) for next iter (broadcast, conflict-free)
#pragma unroll
    for (int kt = 0; kt < 4; kt++)
      pxn[kt] = *(const f32x4*)&ring[((s + 1) & 3) * 64 + kt * 16 + rb];
    // produce px(t+3) into ring; refill raw queue with raw(t+5)
    ring[((s + 3) & 3) * 64 + lane] = __expf(rawq0);
    rawq0 = rawq1;
    {
      int tn = t0 + s + 5; tn = tn > TT - 1 ? TT - 1 : tn;
      rawq1 = Pj[(size_t)tn * NN];
    }
    // D = A · B  (E^T · diag(p) · H)
#pragma unroll
    for (int mt = 0; mt < 4; mt++) {
      f32x4 acc = {0.f, 0.f, 0.f, 0.f};
#pragma unroll
      for (int kt = 0; kt < 4; kt++)
        acc = __builtin_amdgcn_mfma_f32_16x16x16bf16_1k(Af[mt][kt], Bf[kt], acc, 0, 0, 0);
      D[mt] = acc;
    }
#pragma unroll
    for (int kt = 0; kt < 4; kt++) pxc[kt] = pxn[kt];
  }

  // epilogue: H = diag(p_last)·D, renorm, transpose out via LDS
  {
    float hf = __int_as_float(
        __builtin_amdgcn_readfirstlane(__float_as_int(D[0][0] * pxc[0][0])));
    int ef = fexp(hf);
    float sc = ldexpf(1.0f, -ef);
    etot += ef;
#pragma unroll
    for (int mt = 0; mt < 4; mt++) {
      f32x4 d = D[mt]; f32x4 pv = pxc[mt];
      int base = lm * 33 + mt * 8 + q * 2;
      sht[base]     = pkbf(d[0] * pv[0] * sc, d[1] * pv[1] * sc);
      sht[base + 1] = pkbf(d[2] * pv[2] * sc, d[3] * pv[3] * sc);
    }
#pragma unroll
    for (int w = 0; w < 8; w++) {
      unsigned short a0 = ((const unsigned short*)(sht + (2 * w) * 33 + (lane >> 1)))[lane & 1];
      unsigned short a1 = ((const unsigned short*)(sht + (2 * w + 1) * 33 + (lane >> 1)))[lane & 1];
      Hc[w * 64 + lane] = (unsigned)a0 | ((unsigned)a1 << 16);
    }
    if (lane == 0) Eexp[(b * NCH + c) * 4 + g] = etot;
  }
}

// ============================ PHASE 2 + REDUCE =============================
// 128 blocks x 64 threads (1 wave, batch b): 16 sequential chunk mat-vecs,
// 2-chunk register prefetch, LDS a-broadcast (same-wave ordering, no barriers).
__global__ __launch_bounds__(64, 4) void crf_phase2(
    const float* __restrict__ pot, const unsigned* __restrict__ Hg,
    const int* __restrict__ Eexp, const float* __restrict__ score,
    const float* __restrict__ wgt, float* __restrict__ accf,
    unsigned* __restrict__ cnt, float* __restrict__ out) {
  __shared__ __align__(16) float sha[64];
  const int j = threadIdx.x;
  const int b = blockIdx.x;

  float a = __expf(pot[(size_t)b * TT * NN + j]);
  sha[j] = a;
  int atot = 0;

  const unsigned* Hb = Hg + (size_t)b * NCH * 2048;
  unsigned bufA[32], bufB[32];
#pragma unroll
  for (int k = 0; k < 32; k++) bufA[k] = Hb[k * 64 + j];
#pragma unroll
  for (int k = 0; k < 32; k++) bufB[k] = Hb[2048 + k * 64 + j];

#pragma unroll
  for (int cc = 0; cc < NCH; cc += 2) {
#pragma unroll
    for (int half = 0; half < 2; half++) {
      const int c = cc + half;
      unsigned* cur = half ? bufB : bufA;
      // S_g[j] = sum over cols in group g of H[j][col] * a[col]
      float S[4] = {0.f, 0.f, 0.f, 0.f};
#pragma unroll
      for (int w4 = 0; w4 < 16; w4++) {
        f32x4 av = *(const f32x4*)&sha[w4 * 4];
        unsigned r0 = cur[2 * w4], r1 = cur[2 * w4 + 1];
        S[w4 >> 2] += __uint_as_float(r0 << 16) * av[0] +
                      __uint_as_float(r0 & 0xffff0000u) * av[1] +
                      __uint_as_float(r1 << 16) * av[2] +
                      __uint_as_float(r1 & 0xffff0000u) * av[3];
      }
      const int eb = b * 64 + c * 4;
      int e0 = Eexp[eb + 0], e1 = Eexp[eb + 1], e2 = Eexp[eb + 2], e3 = Eexp[eb + 3];
      int em = max(max(e0, e1), max(e2, e3));
      float Sc = ldexpf(S[0], e0 - em) + ldexpf(S[1], e1 - em) +
                 ldexpf(S[2], e2 - em) + ldexpf(S[3], e3 - em);
      int er = fexp(__int_as_float(
          __builtin_amdgcn_readfirstlane(__float_as_int(Sc))));
      a = ldexpf(Sc, -er);
      atot += em + er;
      sha[j] = a;  // same-wave DS ordering: visible to next chunk's reads
      // refill this buffer with chunk c+2
      if (c + 2 < NCH) {
        const unsigned* Hn = Hb + (size_t)(c + 2) * 2048;
#pragma unroll
        for (int k = 0; k < 32; k++) cur[k] = Hn[k * 64 + j];
      }
    }
  }

  float ssum = wave_sum64(a);
  if (j == 0) {
    float lognorm = __logf(ssum) + (float)atot * 0.69314718055994530942f;
    float loss = -(score[b] - lognorm) * wgt[b];
    atomicAdd(accf, loss * (1.0f / BB));
    __threadfence();
    unsigned old = atomicAdd(cnt, 1u);
    if (old == BB - 1) out[0] = atomicAdd(accf, 0.0f);
  }
}

// ===================== R1 fallback (ws too small) =====================
__global__ __launch_bounds__(64) void crf_main_fb(
    const float* __restrict__ pot, const int* __restrict__ tags,
    const int* __restrict__ seqlen, const float* __restrict__ K,
    float* __restrict__ ws) {
  __shared__ float sh[4096];
  const int lane = threadIdx.x;
  const int blk = blockIdx.x;
  if (blk < BB) {
    const int b = blk;
    const int L = seqlen[b];
    float Ec[64];
#pragma unroll
    for (int i = 0; i < 64; i++) Ec[i] = __expf(K[i * 64 + lane]);
    const float* pb = pot + (size_t)b * TT * NN + lane;
    float av = __expf(pb[0]);
    int etot = 0;
    sh[lane] = av;
    float pf[8];
#pragma unroll
    for (int k = 0; k < 8; k++) pf[k] = pb[(size_t)(1 + k) * 64];
    for (int t0 = 1; t0 < L; t0 += 8) {
#pragma unroll
      for (int k = 0; k < 8; k++) {
        const int t = t0 + k;
        const float pe = __expf(pf[k]);
        int tn = t + 8; tn = tn > (TT - 1) ? (TT - 1) : tn;
        pf[k] = pb[(size_t)tn * 64];
        const float4* arow = (const float4*)(sh + ((t - 1) & 1) * 64);
        float s[8];
#pragma unroll
        for (int qq = 0; qq < 8; qq++) s[qq] = 0.0f;
#pragma unroll
        for (int qq = 0; qq < 16; qq++) {
          float4 a4 = arow[qq];
          float pr = fmaf(a4.x, Ec[4 * qq + 0], fmaf(a4.y, Ec[4 * qq + 1],
                     fmaf(a4.z, Ec[4 * qq + 2], a4.w * Ec[4 * qq + 3])));
          s[qq & 7] += pr;
        }
        float S = ((s[0] + s[1]) + (s[2] + s[3])) + ((s[4] + s[5]) + (s[6] + s[7]));
        if (t < L) {
          av = S * pe;
          if ((t & 3) == 0) {
            float m0 = __shfl(av, 0, 64);
            int e = ((__float_as_int(m0) >> 23) & 0xff) - 126;
            av = ldexpf(av, -e);
            etot += e;
          }
        }
        sh[(t & 1) * 64 + lane] = av;
      }
    }
    float ssum = wave_sum64(av);
    if (lane == 0) ws[b] = __logf(ssum) + (float)etot * 0.69314718055994530942f;
  } else {
    const int b = blk - BB;
    const int L = seqlen[b];
    for (int i = lane; i < 4096; i += 64) sh[i] = K[i];
    __syncthreads();
    const int* tg = tags + b * TT;
    const float* pbase = pot + (size_t)b * TT * NN;
    float acc = 0.0f;
    for (int t = lane; t < TT; t += 64) {
      if (t < L) {
        int cc = tg[t];
        float u = pbase[(size_t)t * 64 + cc];
        float tr = 0.0f;
        if (t >= 1) tr = sh[tg[t - 1] * 64 + cc];
        acc += u + tr;
      }
    }
    acc = wave_sum64(acc);
    if (lane == 0) ws[BB + b] = acc;
  }
}

__global__ __launch_bounds__(128) void crf_combine_fb(
    const float* __restrict__ ws, const float* __restrict__ wgt,
    float* __restrict__ out) {
  const int i = threadIdx.x;
  float lv = -(ws[BB + i] - ws[i]) * wgt[i];
  lv = wave_sum64(lv);
  __shared__ float p[2];
  if ((i & 63) == 0) p[i >> 6] = lv;
  __syncthreads();
  if (i == 0) out[0] = (p[0] + p[1]) * (1.0f / 128.0f);
}

extern "C" void kernel_launch(void* const* d_in, const int* in_sizes, int n_in,
                              void* d_out, int out_size, void* d_ws, size_t ws_size,
                              hipStream_t stream) {
  const float* pot    = (const float*)d_in[0];
  const int*   tags   = (const int*)d_in[1];
  const int*   seqlen = (const int*)d_in[2];
  const float* K      = (const float*)d_in[3];
  const float* wgt    = (const float*)d_in[4];

  const size_t HG_DW = (size_t)BB * NCH * 2048;  // 16 MB of bf16-pair dwords
  const size_t NEXP  = (size_t)BB * NCH * 4;
  const size_t need  = (HG_DW + NEXP + BB + 2) * 4;

  if (ws_size >= need) {
    unsigned* Hg    = (unsigned*)d_ws;
    int* Eexp       = (int*)(Hg + HG_DW);
    float* score    = (float*)(Eexp + NEXP);
    float* accf     = score + BB;
    unsigned* cntp  = (unsigned*)(accf + 1);
    crf_phase1<<<BB + BB * NCH * 4, 64, 0, stream>>>(pot, tags, seqlen, K, Hg, Eexp,
                                                     score, accf, cntp);
    crf_phase2<<<BB, 64, 0, stream>>>(pot, Hg, Eexp, score, wgt, accf, cntp,
                                      (float*)d_out);
  } else {
    float* ws = (float*)d_ws;
    crf_main_fb<<<256, 64, 0, stream>>>(pot, tags, seqlen, K, ws);
    crf_combine_fb<<<1, 128, 0, stream>>>(ws, wgt, (float*)d_out);
  }
}